// Round 8
// baseline (6186.981 us; speedup 1.0000x reference)
//
#include <hip/hip_runtime.h>
#include <hip/hip_cooperative_groups.h>
#include <cmath>

namespace cg = cooperative_groups;

#define SEQ   512
#define BATCH 64
#define DIN   1024
#define DH    1024

// h replica geometry: 8 replicas, stride 256KB + 4352B (odd multiple of 256B
// so replicas map to different L3 slices; a 2^18 stride would alias).
#define NREP   8
#define HS4    16657          // float4 stride between replicas (16384 + 273)
#define HSF    (HS4 * 4)      // float stride                (66628)
#define PS4    (NREP * HS4)   // float4 stride between ping/pong parities
#define PSF    (PS4 * 4)

typedef float f4 __attribute__((ext_vector_type(4)));

// ---------------------------------------------------------------------------
// Phase 1: x_proj = X @ W_ih^T + b_ih + b_hh  -> d_out[s][b][h]   (unchanged)
// ---------------------------------------------------------------------------
__global__ __launch_bounds__(256) void proj_kernel(
    const float* __restrict__ X, const float* __restrict__ W,
    const float* __restrict__ b_ih, const float* __restrict__ b_hh,
    float* __restrict__ C) {
  __shared__ float As[64][17];
  __shared__ float Bs[64][17];
  const int m0 = blockIdx.x * 64;
  const int n0 = blockIdx.y * 64;
  const int tid = threadIdx.x;
  const int tm = tid >> 4;
  const int tn = tid & 15;
  const int lrow = tid >> 2;
  const int lk4  = (tid & 3) * 4;

  float acc[4][4];
#pragma unroll
  for (int i = 0; i < 4; ++i)
#pragma unroll
    for (int j = 0; j < 4; ++j) acc[i][j] = 0.f;

  for (int kt = 0; kt < DIN; kt += 16) {
    float4 av = *(const float4*)(X + (size_t)(m0 + lrow) * DIN + kt + lk4);
    float4 bv = *(const float4*)(W + (size_t)(n0 + lrow) * DIN + kt + lk4);
    __syncthreads();
    As[lrow][lk4 + 0] = av.x; As[lrow][lk4 + 1] = av.y;
    As[lrow][lk4 + 2] = av.z; As[lrow][lk4 + 3] = av.w;
    Bs[lrow][lk4 + 0] = bv.x; Bs[lrow][lk4 + 1] = bv.y;
    Bs[lrow][lk4 + 2] = bv.z; Bs[lrow][lk4 + 3] = bv.w;
    __syncthreads();
#pragma unroll
    for (int kk = 0; kk < 16; ++kk) {
      float a[4], b[4];
#pragma unroll
      for (int i = 0; i < 4; ++i) a[i] = As[tm * 4 + i][kk];
#pragma unroll
      for (int j = 0; j < 4; ++j) b[j] = Bs[tn * 4 + j][kk];
#pragma unroll
      for (int i = 0; i < 4; ++i)
#pragma unroll
        for (int j = 0; j < 4; ++j) acc[i][j] += a[i] * b[j];
    }
  }

#pragma unroll
  for (int j = 0; j < 4; ++j) {
    const int n = n0 + tn * 4 + j;
    const float bias = b_ih[n] + b_hh[n];
#pragma unroll
    for (int i = 0; i < 4; ++i) {
      const int m = m0 + tm * 4 + i;
      C[(size_t)m * DH + n] = acc[i][j] + bias;
    }
  }
}

// ---------------------------------------------------------------------------
// h0 -> quad-packed transposed layout hT4[k>>2][b][k&3] into R replicas of
// parity-0; zeroes the barrier state. R=1 when ws is too small for replicas.
// ---------------------------------------------------------------------------
__global__ __launch_bounds__(256) void transpose_h0(
    const float* __restrict__ h0, float* __restrict__ hb, unsigned* cnt,
    int R) {
  const int idx = blockIdx.x * 256 + threadIdx.x;  // 0..16383
  const int k4 = idx >> 6;
  const int b = idx & 63;
  float4 v = *(const float4*)(h0 + (size_t)b * DH + (k4 << 2));
  float4* h4 = (float4*)hb;
  for (int r = 0; r < R; ++r) h4[(size_t)r * HS4 + idx] = v;
  if (cnt != nullptr && blockIdx.x == 0 && threadIdx.x < 160) {
    __hip_atomic_store(&cnt[threadIdx.x], 0u, __ATOMIC_RELAXED,
                       __HIP_MEMORY_SCOPE_AGENT);
  }
}

// ---------------------------------------------------------------------------
// Phase 2 FAST PATH (round-7 verified structure + 8-way replicated h
// exchange). No grid.sync -> no L2 invalidate; W_hh stays K$/L2-hot. h is
// exchanged through L3 with sc0+sc1 loads/stores. NEW: finalize stores h to
// 8 replicas (odd-256B-offset stride -> distinct L3 slices); each block
// reads replica bx&7, spreading the 256-CU broadcast of a 4096-line
// footprint across 8x the L3 slice ports.
// Barrier: sense-reversing two-level (8 leaves + root + flag), agent-scope
// relaxed atomics, state-neutral after 512 flips, spin guard.
// 256 blocks x 1024 thr, 16 waves split K 16 ways; 16 h-float4 per lane in
// flight; LDS reduce stride-1093 (conflict-free writes, 2-way reads = free).
// ---------------------------------------------------------------------------
__global__ __launch_bounds__(1024, 4) void rnn_fast(
    const float* __restrict__ W_hh, float* __restrict__ out,
    float* __restrict__ hb, unsigned* cnt) {
  __shared__ float red[4 * 1093];  // idx = jj*1093 + b*17 + u
  const int tid = threadIdx.x;
  const int bx = blockIdx.x;
  const int b = tid & 63;
  const int wv = tid >> 6;                                   // 0..15
  const int j0 = __builtin_amdgcn_readfirstlane(bx << 2);
  const float* __restrict__ w0 = W_hh + (size_t)j0 * DH;
  const float* __restrict__ w1 = w0 + DH;
  const float* __restrict__ w2 = w1 + DH;
  const float* __restrict__ w3 = w2 + DH;
  const int kq4 = __builtin_amdgcn_readfirstlane(wv << 4);   // float4 base
  const int fjj = tid & 3;
  const int fb  = tid >> 2;
  const int rep = __builtin_amdgcn_readfirstlane(bx & (NREP - 1));
  unsigned* leaf = cnt + ((bx & 7) << 4);   // 8 leaves, 64B apart
  unsigned* root = cnt + 128;
  unsigned* flag = cnt + 144;
  int sense = 1;
  bool dead = false;

  for (int t = 0; t < SEQ; ++t) {
    // read base: this block's replica of the current parity
    const f4* __restrict__ hp4 =
        (const f4*)hb + ((t & 1) ? PS4 : 0) + (size_t)rep * HS4;
    // write base: replica 0 of the other parity (floats)
    float* __restrict__ hn = hb + ((t & 1) ? 0 : PSF);
    const f4* pb = hp4 + (kq4 << 6) + b;

    // 16 L3-coherent (sc0 sc1) h loads, all in flight as named registers.
    f4 q0, q1, q2, q3, q4, q5, q6, q7, q8, q9, q10, q11, q12, q13, q14, q15;
#define LQ(i) asm volatile("global_load_dwordx4 %0, %1, off sc0 sc1" \
                           : "=v"(q##i) : "v"(pb + ((i) << 6)) : "memory");
    LQ(0)  LQ(1)  LQ(2)  LQ(3)  LQ(4)  LQ(5)  LQ(6)  LQ(7)
    LQ(8)  LQ(9)  LQ(10) LQ(11) LQ(12) LQ(13) LQ(14) LQ(15)
#undef LQ

    // xp (block-private, normally cached); drains with the h loads.
    size_t ob = 0;
    float xp = 0.f;
    if (tid < 256) {
      ob = ((size_t)t * BATCH + fb) * DH + j0 + fjj;
      xp = out[ob];
    }

    // Data-chained drain: FMAs read the redefined q's -> cannot hoist.
    asm volatile("s_waitcnt vmcnt(0)"
                 : "+v"(q0), "+v"(q1), "+v"(q2), "+v"(q3),
                   "+v"(q4), "+v"(q5), "+v"(q6), "+v"(q7),
                   "+v"(q8), "+v"(q9), "+v"(q10), "+v"(q11),
                   "+v"(q12), "+v"(q13), "+v"(q14), "+v"(q15)
                 :: "memory");

    float a0 = 0.f, a1 = 0.f, a2 = 0.f, a3 = 0.f;
#define CH(Q, c) { \
    const int k = (kq4 + (c)) << 2; \
    a0 = fmaf(w0[k + 0], Q.x, a0); a1 = fmaf(w1[k + 0], Q.x, a1); \
    a2 = fmaf(w2[k + 0], Q.x, a2); a3 = fmaf(w3[k + 0], Q.x, a3); \
    a0 = fmaf(w0[k + 1], Q.y, a0); a1 = fmaf(w1[k + 1], Q.y, a1); \
    a2 = fmaf(w2[k + 1], Q.y, a2); a3 = fmaf(w3[k + 1], Q.y, a3); \
    a0 = fmaf(w0[k + 2], Q.z, a0); a1 = fmaf(w1[k + 2], Q.z, a1); \
    a2 = fmaf(w2[k + 2], Q.z, a2); a3 = fmaf(w3[k + 2], Q.z, a3); \
    a0 = fmaf(w0[k + 3], Q.w, a0); a1 = fmaf(w1[k + 3], Q.w, a1); \
    a2 = fmaf(w2[k + 3], Q.w, a2); a3 = fmaf(w3[k + 3], Q.w, a3); \
  }
    CH(q0, 0)   CH(q1, 1)   CH(q2, 2)   CH(q3, 3)
    CH(q4, 4)   CH(q5, 5)   CH(q6, 6)   CH(q7, 7)
    CH(q8, 8)   CH(q9, 9)   CH(q10, 10) CH(q11, 11)
    CH(q12, 12) CH(q13, 13) CH(q14, 14) CH(q15, 15)
#undef CH

    // cross-wave reduce: writes conflict-free (17-stride), reads 2-way
    red[0 * 1093 + b * 17 + wv] = a0;
    red[1 * 1093 + b * 17 + wv] = a1;
    red[2 * 1093 + b * 17 + wv] = a2;
    red[3 * 1093 + b * 17 + wv] = a3;
    __syncthreads();

    if (tid < 256) {
      float s = 0.f;
#pragma unroll
      for (int u = 0; u < 16; ++u) s += red[fjj * 1093 + fb * 17 + u];
      const float v = tanhf(xp + s);
      out[ob] = v;  // block-private, plain cached store
      // quad-packed h store to all 8 replicas (sc0 sc1, straight to L3)
      float* dst = hn + ((size_t)bx << 8) + tid;
#pragma unroll
      for (int r = 0; r < NREP; ++r) {
        asm volatile("global_store_dword %0, %1, off sc0 sc1"
                     :: "v"(dst + (size_t)r * HSF), "v"(v) : "memory");
      }
      if (t == SEQ - 1) {
        float* hl = out + (size_t)SEQ * BATCH * DH;
        hl[(size_t)fb * DH + j0 + fjj] = v;
      }
    }

    // ---- barrier (512 flips -> state-neutral for replay) ----
    asm volatile("s_waitcnt vmcnt(0)" ::: "memory");  // h stores in L3
    __syncthreads();                                  // whole block drained
    if (!dead && tid == 0) {
      unsigned old = __hip_atomic_fetch_add(leaf, 1u, __ATOMIC_RELAXED,
                                            __HIP_MEMORY_SCOPE_AGENT);
      if (old == 31u) {  // last of this leaf: reset leaf, then bump root
        __hip_atomic_store(leaf, 0u, __ATOMIC_RELAXED,
                           __HIP_MEMORY_SCOPE_AGENT);
        asm volatile("s_waitcnt vmcnt(0)" ::: "memory");
        unsigned rold = __hip_atomic_fetch_add(root, 1u, __ATOMIC_RELAXED,
                                               __HIP_MEMORY_SCOPE_AGENT);
        if (rold == 7u) {  // last overall: reset root, then release
          __hip_atomic_store(root, 0u, __ATOMIC_RELAXED,
                             __HIP_MEMORY_SCOPE_AGENT);
          asm volatile("s_waitcnt vmcnt(0)" ::: "memory");
          __hip_atomic_store(flag, (unsigned)sense, __ATOMIC_RELAXED,
                             __HIP_MEMORY_SCOPE_AGENT);
        }
      }
      int guard = 0;
      while (__hip_atomic_load(flag, __ATOMIC_RELAXED,
                               __HIP_MEMORY_SCOPE_AGENT) != (unsigned)sense) {
        __builtin_amdgcn_s_sleep(1);
        if (++guard > (1 << 20)) { dead = true; break; }  // bail, don't hang
      }
    }
    sense ^= 1;
    __syncthreads();
  }
}

// ---------------------------------------------------------------------------
// Fallback step body (round-6 verified; compact non-replicated h layout)
// ---------------------------------------------------------------------------
__device__ __forceinline__ void rnn_step_body(
    float (*red)[4][64], const float4* __restrict__ hp,
    float* __restrict__ hn, const float* __restrict__ W_hh,
    float* __restrict__ out, int t, int bx, int tid) {
  const int b = tid & 63;
  const int wv = tid >> 6;
  const int j0 = __builtin_amdgcn_readfirstlane(bx << 2);
  const float* __restrict__ w0 = W_hh + (size_t)j0 * DH;
  const float* __restrict__ w1 = w0 + DH;
  const float* __restrict__ w2 = w1 + DH;
  const float* __restrict__ w3 = w2 + DH;
  const int kq4 = __builtin_amdgcn_readfirstlane(wv << 4);
  const int fjj = tid & 3;
  const int fb  = tid >> 2;

  const float4 q0  = hp[((kq4 +  0) << 6) + b];
  const float4 q1  = hp[((kq4 +  1) << 6) + b];
  const float4 q2  = hp[((kq4 +  2) << 6) + b];
  const float4 q3  = hp[((kq4 +  3) << 6) + b];
  const float4 q4  = hp[((kq4 +  4) << 6) + b];
  const float4 q5  = hp[((kq4 +  5) << 6) + b];
  const float4 q6  = hp[((kq4 +  6) << 6) + b];
  const float4 q7  = hp[((kq4 +  7) << 6) + b];
  const float4 q8  = hp[((kq4 +  8) << 6) + b];
  const float4 q9  = hp[((kq4 +  9) << 6) + b];
  const float4 q10 = hp[((kq4 + 10) << 6) + b];
  const float4 q11 = hp[((kq4 + 11) << 6) + b];
  const float4 q12 = hp[((kq4 + 12) << 6) + b];
  const float4 q13 = hp[((kq4 + 13) << 6) + b];
  const float4 q14 = hp[((kq4 + 14) << 6) + b];
  const float4 q15 = hp[((kq4 + 15) << 6) + b];

  size_t ob = 0;
  float xp = 0.f;
  if (tid < 256) {
    ob = ((size_t)t * BATCH + fb) * DH + j0 + fjj;
    xp = out[ob];
  }

  float a0 = 0.f, a1 = 0.f, a2 = 0.f, a3 = 0.f;
#define CH(Q, c) { \
    const int k = (kq4 + (c)) << 2; \
    a0 = fmaf(w0[k + 0], Q.x, a0); a1 = fmaf(w1[k + 0], Q.x, a1); \
    a2 = fmaf(w2[k + 0], Q.x, a2); a3 = fmaf(w3[k + 0], Q.x, a3); \
    a0 = fmaf(w0[k + 1], Q.y, a0); a1 = fmaf(w1[k + 1], Q.y, a1); \
    a2 = fmaf(w2[k + 1], Q.y, a2); a3 = fmaf(w3[k + 1], Q.y, a3); \
    a0 = fmaf(w0[k + 2], Q.z, a0); a1 = fmaf(w1[k + 2], Q.z, a1); \
    a2 = fmaf(w2[k + 2], Q.z, a2); a3 = fmaf(w3[k + 2], Q.z, a3); \
    a0 = fmaf(w0[k + 3], Q.w, a0); a1 = fmaf(w1[k + 3], Q.w, a1); \
    a2 = fmaf(w2[k + 3], Q.w, a2); a3 = fmaf(w3[k + 3], Q.w, a3); \
  }
  CH(q0, 0)   CH(q1, 1)   CH(q2, 2)   CH(q3, 3)
  CH(q4, 4)   CH(q5, 5)   CH(q6, 6)   CH(q7, 7)
  CH(q8, 8)   CH(q9, 9)   CH(q10, 10) CH(q11, 11)
  CH(q12, 12) CH(q13, 13) CH(q14, 14) CH(q15, 15)
#undef CH

  red[wv][0][b] = a0; red[wv][1][b] = a1;
  red[wv][2][b] = a2; red[wv][3][b] = a3;
  __syncthreads();

  if (tid < 256) {
    float s = 0.f;
#pragma unroll
    for (int u = 0; u < 16; ++u) s += red[u][fjj][fb];
    const float v = tanhf(xp + s);
    out[ob] = v;
    hn[((size_t)bx << 8) + tid] = v;
    if (t == SEQ - 1) {
      float* hl = out + (size_t)SEQ * BATCH * DH;
      hl[(size_t)fb * DH + j0 + fjj] = v;
    }
  }
}

__global__ __launch_bounds__(1024) void rnn_persistent_cg(
    const float* __restrict__ W_hh, float* __restrict__ out,
    float* __restrict__ hA, float* __restrict__ hB) {
  __shared__ float red[16][4][64];
  cg::grid_group grid = cg::this_grid();
  const int tid = threadIdx.x;
  const int bx = blockIdx.x;
  for (int t = 0; t < SEQ; ++t) {
    const float4* hp = (const float4*)((t & 1) ? hB : hA);
    float* hn = (t & 1) ? hA : hB;
    rnn_step_body(red, hp, hn, W_hh, out, t, bx, tid);
    grid.sync();
  }
}

__global__ __launch_bounds__(1024) void rnn_step_kernel(
    const float* __restrict__ hTprev, float* __restrict__ hTnext,
    const float* __restrict__ W_hh, float* __restrict__ out, int t) {
  __shared__ float red[16][4][64];
  rnn_step_body(red, (const float4*)hTprev, hTnext, W_hh, out, t,
                blockIdx.x, threadIdx.x);
}

extern "C" void kernel_launch(void* const* d_in, const int* in_sizes, int n_in,
                              void* d_out, int out_size, void* d_ws,
                              size_t ws_size, hipStream_t stream) {
  const float* x    = (const float*)d_in[0];
  const float* h0   = (const float*)d_in[1];
  const float* W_ih = (const float*)d_in[2];
  const float* b_ih = (const float*)d_in[3];
  const float* W_hh = (const float*)d_in[4];
  const float* b_hh = (const float*)d_in[5];
  float* out = (float*)d_out;
  unsigned* cnt = (unsigned*)d_ws;            // 1KB barrier state
  float* hb = (float*)d_ws + 256;             // h exchange region
  // fast path needs: 1KB + 2 parities * 8 replicas * (256KB + 4352B pad)
  const size_t need = 1024 + (size_t)2 * NREP * HSF * sizeof(float);
  const bool fast_ok = ws_size >= need;
  // fallback compact layout needs 1KB + 512KB
  const bool fb_ok = ws_size >= 1024 + (size_t)2 * DH * BATCH * sizeof(float);

  hipLaunchKernelGGL(proj_kernel, dim3(512, 16), dim3(256), 0, stream,
                     x, W_ih, b_ih, b_hh, out);
  hipLaunchKernelGGL(transpose_h0, dim3(64), dim3(256), 0, stream, h0, hb,
                     fast_ok ? cnt : (unsigned*)nullptr, fast_ok ? NREP : 1);

  const float* W_hh_p = W_hh;
  float* out_p = out;
  float* hb_p = hb;
  float* hA_p = hb;                           // fallback compact buffers
  float* hB_p = hb + (size_t)DH * BATCH;
  unsigned* cnt_p = cnt;
  hipError_t err = hipErrorUnknown;
  if (fast_ok) {
    void* args[] = {(void*)&W_hh_p, (void*)&out_p, (void*)&hb_p,
                    (void*)&cnt_p};
    err = hipLaunchCooperativeKernel(reinterpret_cast<void*>(rnn_fast),
                                     dim3(256), dim3(1024), args, 0, stream);
  }
  if (err != hipSuccess && fb_ok) {
    void* args2[] = {(void*)&W_hh_p, (void*)&out_p, (void*)&hA_p,
                     (void*)&hB_p};
    err = hipLaunchCooperativeKernel(
        reinterpret_cast<void*>(rnn_persistent_cg), dim3(256), dim3(1024),
        args2, 0, stream);
  }
  if (err != hipSuccess) {
    for (int t = 0; t < SEQ; ++t) {
      const float* src = (t & 1) ? hB_p : hA_p;
      float* dst = (t & 1) ? hA_p : hB_p;
      hipLaunchKernelGGL(rnn_step_kernel, dim3(256), dim3(1024), 0, stream,
                         src, dst, W_hh, out, t);
    }
  }
}